// Round 6
// baseline (17755.501 us; speedup 1.0000x reference)
//
#include <hip/hip_runtime.h>
#include <stdint.h>

typedef unsigned int u32;
typedef unsigned short u16;

// ---- problem dims ----
#define TT     256
#define LATENT 512
#define NBLK   64     // grid size; all blocks co-resident (<=256 CUs)
// padded k2 (bf16-pair word) counts per layer, all multiples of 4 (uint4 groups)
#define KZ2P 272    // LSTM xc: slots [xt(9),pad, h0..h358, pad, h359..h511, pad...] = 544 slots
#define K0R  128    // L0 xc: 113 real words
#define K1R  192    // L1 xc: 180 real words
#define K2R  160    // L2 xc: 149 real words
// ws layout (u32 words): [sync 64 words][weights]. LSTM region is [k2][2048]
// with GATE-INTERLEAVED rows: ws row r = 4v+g <-> original z row v + 512*g.
// CfC regions are row-major [tau][K], tau = 4*o + m, m in {w1,w2,wa,wb}.
#define WSY   64                    // sync region (256 B): [0]=arrive, [32]=generation
#define OFF_A (KZ2P*2048)           // 557056  (end LSTM, relative to weight base)
#define OFF_B (OFF_A + 864*K0R)     // 667648  (end L0)
#define OFF_C (OFF_B + 572*K1R)     // 777472  (end L1)
#define WS_WORDS (OFF_C + 612*K2R)  // 875392  (~3.34 MiB weights)

__device__ __forceinline__ u16 f2bf(float f){
  u32 u = __builtin_bit_cast(u32, f);
  u += 0x7FFFu + ((u >> 16) & 1u);     // RNE
  return (u16)(u >> 16);
}
__device__ __forceinline__ u32 packbf(float lo, float hi){
  return (u32)f2bf(lo) | ((u32)f2bf(hi) << 16);
}
__device__ __forceinline__ float bdot(u32 a, u32 b, float c){
  float d;
  asm("v_dot2_f32_bf16 %0, %1, %2, %3" : "=v"(d) : "v"(a), "v"(b), "v"(c));
  return d;
}
__device__ __forceinline__ float sigm(float x){ return 1.0f/(1.0f + __expf(-x)); }
__device__ __forceinline__ float tanh_(float x){ return 1.0f - 2.0f/(1.0f + __expf(2.0f*x)); }

// Perf-only soft barrier: keeps the 64 persistent blocks in per-step lockstep so
// co-XCD blocks share one L2 fetch stream. Bounded spin -> deadlock impossible;
// carries NO data dependency (blocks share nothing), so results are unaffected.
__device__ __forceinline__ void soft_sync(u32* sc, u32 target){
  if (threadIdx.x == 0){
    u32 n = __hip_atomic_fetch_add(&sc[0], 1u, __ATOMIC_ACQ_REL, __HIP_MEMORY_SCOPE_AGENT) + 1u;
    if (n == (u32)NBLK){
      __hip_atomic_store(&sc[0], 0u, __ATOMIC_RELAXED, __HIP_MEMORY_SCOPE_AGENT);
      __hip_atomic_fetch_add(&sc[32], 1u, __ATOMIC_RELEASE, __HIP_MEMORY_SCOPE_AGENT);
    } else {
      int guard = 1 << 21;
      while (__hip_atomic_load(&sc[32], __ATOMIC_ACQUIRE, __HIP_MEMORY_SCOPE_AGENT) < target
             && --guard) __builtin_amdgcn_s_sleep(2);
    }
  }
  __syncthreads();
}

// ---------------- weight value mappings (proven in rounds 3/4/5) ----------------
__device__ __forceinline__ float lstmval(const float* wi, const float* wr, int r, int s){
  if (s < 9)  return wi[r*9 + s];
  if (s == 9 || s == 369 || s >= 523) return 0.f;
  if (s < 369) return wr[r*512 + s - 10];   // h0..h358
  return wr[r*512 + s - 11];                // h359..h511
}
__device__ __forceinline__ float l0val(const float* W, const int* M, int o, int k){
  if (k == 9 || k >= 226) return 0.f;
  int ki = (k < 9) ? k : k - 1;                 // D=225
  float w = W[o*225 + ki];
  if (M) w *= (float)M[o*225 + ki];
  return w;
}
__device__ __forceinline__ float l1val(const float* W, const int* M, int o, int k){
  if (k >= 359) return 0.f;                     // D=359
  float w = W[o*359 + k];
  if (M) w *= (float)M[o*359 + k];
  return w;
}
__device__ __forceinline__ float l2val(const float* W, const int* M, int o, int k){
  if (k == 143 || k == 144 || k >= 298) return 0.f;  // D=296; slot144 = h358 (zero weight)
  int ki = (k < 143) ? k : k - 2;
  float w = W[o*296 + ki];
  if (M) w *= (float)M[o*296 + ki];
  return w;
}

__global__ void prep_kernel(
    const float* __restrict__ wi, const float* __restrict__ wr,
    const float* __restrict__ w10,const float* __restrict__ w20,const float* __restrict__ wa0,const float* __restrict__ wb0,const int* __restrict__ m0,
    const float* __restrict__ w11,const float* __restrict__ w21,const float* __restrict__ wa1,const float* __restrict__ wb1,const int* __restrict__ m1,
    const float* __restrict__ w12,const float* __restrict__ w22,const float* __restrict__ wa2,const float* __restrict__ wb2,const int* __restrict__ m2,
    u32* __restrict__ ws)
{
  for (int g = blockIdx.x*blockDim.x + threadIdx.x; g < WSY + WS_WORDS; g += gridDim.x*blockDim.x){
    if (g < WSY){ ws[g] = 0u; continue; }      // zero sync region every launch
    int i = g - WSY;
    float lo = 0.f, hi = 0.f;
    if (i < OFF_A){
      int k2 = i >> 11, r = i & 2047;
      int orig = (r >> 2) + ((r & 3) << 9);     // gate-interleaved
      lo = lstmval(wi, wr, orig, 2*k2);
      hi = lstmval(wi, wr, orig, 2*k2+1);
    } else if (i < OFF_B){
      int loc = i - OFF_A;
      int r = loc >> 7, k2 = loc & 127;         // K0R=128
      int o = r >> 2, m = r & 3;
      const float* W = (m==0)?w10:(m==1)?w20:(m==2)?wa0:wb0;
      const int* M = (m < 2) ? m0 : nullptr;
      lo = l0val(W, M, o, 2*k2); hi = l0val(W, M, o, 2*k2+1);
    } else if (i < OFF_C){
      int loc = i - OFF_B;
      int r = loc / K1R, k2 = loc - r*K1R;
      int o = r >> 2, m = r & 3;
      const float* W = (m==0)?w11:(m==1)?w21:(m==2)?wa1:wb1;
      const int* M = (m < 2) ? m1 : nullptr;
      lo = l1val(W, M, o, 2*k2); hi = l1val(W, M, o, 2*k2+1);
    } else {
      int loc = i - OFF_C;
      int r = loc / K2R, k2 = loc - r*K2R;
      int o = r >> 2, m = r & 3;
      const float* W = (m==0)?w12:(m==1)?w22:(m==2)?wa2:wb2;
      const int* M = (m < 2) ? m2 : nullptr;
      lo = l2val(W, M, o, 2*k2); hi = l2val(W, M, o, 2*k2+1);
    }
    ws[g] = packbf(lo, hi);
  }
}

// ---------------- persistent recurrent kernel ----------------
// grid 64, block 1024. thread: b = tid&1, o/v = tid>>1. Adjacent lanes (b=0/1)
// read the SAME weight address -> coalescer dedup. Weights stream global->VGPR.
// Per-step global soft lockstep keeps co-XCD blocks sharing one fetch stream.
__global__ __launch_bounds__(1024) void liquid_rnn(
    const float* __restrict__ x, const float* __restrict__ dtp,
    const float* __restrict__ lstm_bi,
    const float* __restrict__ b10, const float* __restrict__ b20,
    const float* __restrict__ ba0, const float* __restrict__ bb0,
    const float* __restrict__ b11, const float* __restrict__ b21,
    const float* __restrict__ ba1, const float* __restrict__ bb1,
    const float* __restrict__ b12, const float* __restrict__ b22,
    const float* __restrict__ ba2, const float* __restrict__ bb2,
    u32* __restrict__ wsfull, float* __restrict__ out)
{
  __shared__ u32 hz[2][KZ2P];     // LSTM xc words: [xt(5) | i0(108) | i1(72) | i2(77) | pad]
  __shared__ u32 xc0[2][K0R];     // L0 xc: [xt(5) | hl 0..215 (108) | pad]
  __shared__ u32 xc1[2][K1R];     // L1 xc: [i0 (108) | hl 216..359 (72) | pad]
  __shared__ u32 xc2[2][K2R];     // L2 xc: [i1 (72) | hl-tail (77) | pad]
  __shared__ float outh[2][512];  // final-step h staging

  const int tid = threadIdx.x;
  const int b   = tid & 1;
  const int v   = tid >> 1;
  const int bg  = blockIdx.x*2 + b;
  const int w   = tid >> 6;

  u32* sync = wsfull;
  const u32* ws = wsfull + WSY;

  // hoisted biases (gate order i, ig, fg, og)
  const float lb0 = lstm_bi[v], lb1 = lstm_bi[v+512];
  const float lb2 = lstm_bi[v+1024], lb3 = lstm_bi[v+1536];
  float cb10=0,cb20=0,cba0=0,cbb0=0, cb11=0,cb21=0,cba1=0,cbb1=0, cb12=0,cb22=0,cba2=0,cbb2=0;
  if (v < 216){ cb10=b10[v]; cb20=b20[v]; cba0=ba0[v]; cbb0=bb0[v]; }
  if (v < 143){ cb11=b11[v]; cb21=b21[v]; cba1=ba1[v]; cbb1=bb1[v]; }
  if (v < 153){ cb12=b12[v]; cb22=b22[v]; cba2=ba2[v]; cbb2=bb2[v]; }

  const u32* wz  = ws;
  const u32* wl0 = ws + OFF_A;
  const u32* wl1 = ws + OFF_B;
  const u32* wl2 = ws + OFF_C;

  // init: zero LDS (pads + h0=0), then xt(0)
  if (v < KZ2P) hz[b][v] = 0u;
  if (v < K0R)  xc0[b][v] = 0u;
  if (v < K1R)  xc1[b][v] = 0u;
  if (v < K2R)  xc2[b][v] = 0u;
  if (v < 5){
    int k0 = 2*v, k1 = k0+1;
    float e0 = (k0 < 8) ? x[(size_t)bg*TT*8 + k0] : dtp[(size_t)bg*TT];
    float e1 = (k1 < 8) ? x[(size_t)bg*TT*8 + k1] : 0.f;
    hz[b][v] = packbf(e0, e1);
  }
  float creg = 0.f;
  __syncthreads();

  for (int t = 0; t < TT; ++t){
    // ---- P12: LSTM gates (thread v = neuron v, all 4 gates) + pointwise ----
    {
      float a0=lb0, a1=lb1, a2=lb2, a3=lb3;
      const u32* pw = wz + 4*v;
      #pragma unroll 2
      for (int g = 0; g < KZ2P/4; ++g){
        uint4 av = *(const uint4*)&hz[b][g<<2];
        const u32* q = pw + ((g<<2)*2048);
        uint4 w0 = *(const uint4*)q;
        uint4 w1 = *(const uint4*)(q + 2048);
        uint4 w2 = *(const uint4*)(q + 4096);
        uint4 w3 = *(const uint4*)(q + 6144);
        a0=bdot(w0.x,av.x,a0); a1=bdot(w0.y,av.x,a1); a2=bdot(w0.z,av.x,a2); a3=bdot(w0.w,av.x,a3);
        a0=bdot(w1.x,av.y,a0); a1=bdot(w1.y,av.y,a1); a2=bdot(w1.z,av.y,a2); a3=bdot(w1.w,av.y,a3);
        a0=bdot(w2.x,av.z,a0); a1=bdot(w2.y,av.z,a1); a2=bdot(w2.z,av.z,a2); a3=bdot(w2.w,av.z,a3);
        a0=bdot(w3.x,av.w,a0); a1=bdot(w3.y,av.w,a1); a2=bdot(w3.z,av.w,a2); a3=bdot(w3.w,av.w,a3);
      }
      creg = creg * sigm(a2 + 1.0f) + tanh_(a0) * sigm(a1);
      float hl = tanh_(creg) * sigm(a3);
      float part = __shfl_down(hl, 2);
      if (!(v & 1)){
        int j = v >> 1;  u32 pk = packbf(hl, part);
        if (j < 108) xc0[b][5+j] = pk;
        else if (j < 180){ xc1[b][j] = pk; if (j == 179) xc2[b][72] = pk; }
        else xc2[b][j-107] = pk;
      }
      if (tid < 10) xc0[b][v] = hz[b][v];    // xt prefix for L0
    }
    __syncthreads();
    // ---- P3: CfC L0 (thread o = output o; 4 fused dots + combine) ----
    if (tid < 432){
      float A0=cb10, A1=cb20, A2=cba0, A3=cbb0;
      const u32* p = wl0 + v*(4*K0R);
      #pragma unroll 2
      for (int g = 0; g < K0R/4; ++g){
        uint4 av = *(const uint4*)&xc0[b][g<<2];
        const u32* q = p + (g<<2);
        uint4 w0 = *(const uint4*)q;
        uint4 w1 = *(const uint4*)(q + K0R);
        uint4 w2 = *(const uint4*)(q + 2*K0R);
        uint4 w3 = *(const uint4*)(q + 3*K0R);
        A0=bdot(w0.x,av.x,A0); A0=bdot(w0.y,av.y,A0); A0=bdot(w0.z,av.z,A0); A0=bdot(w0.w,av.w,A0);
        A1=bdot(w1.x,av.x,A1); A1=bdot(w1.y,av.y,A1); A1=bdot(w1.z,av.z,A1); A1=bdot(w1.w,av.w,A1);
        A2=bdot(w2.x,av.x,A2); A2=bdot(w2.y,av.y,A2); A2=bdot(w2.z,av.z,A2); A2=bdot(w2.w,av.w,A2);
        A3=bdot(w3.x,av.x,A3); A3=bdot(w3.y,av.y,A3); A3=bdot(w3.z,av.z,A3); A3=bdot(w3.w,av.w,A3);
      }
      float ti = sigm(A3 - A2);
      float o0 = tanh_(A0)*(1.f - ti) + ti*tanh_(A1);
      float oh = __shfl_down(o0, 2);
      if (!(v & 1)){ u32 pk = packbf(o0, oh); hz[b][5+(v>>1)] = pk; xc1[b][v>>1] = pk; }
      if (t == TT-1) outh[b][v] = o0;
    }
    __syncthreads();
    // ---- P5: CfC L1 -> i1; wave 8 prefetches xt(t+1) ----
    if (tid < 286){
      float A0=cb11, A1=cb21, A2=cba1, A3=cbb1;
      const u32* p = wl1 + v*(4*K1R);
      #pragma unroll 2
      for (int g = 0; g < K1R/4; ++g){
        uint4 av = *(const uint4*)&xc1[b][g<<2];
        const u32* q = p + (g<<2);
        uint4 w0 = *(const uint4*)q;
        uint4 w1 = *(const uint4*)(q + K1R);
        uint4 w2 = *(const uint4*)(q + 2*K1R);
        uint4 w3 = *(const uint4*)(q + 3*K1R);
        A0=bdot(w0.x,av.x,A0); A0=bdot(w0.y,av.y,A0); A0=bdot(w0.z,av.z,A0); A0=bdot(w0.w,av.w,A0);
        A1=bdot(w1.x,av.x,A1); A1=bdot(w1.y,av.y,A1); A1=bdot(w1.z,av.z,A1); A1=bdot(w1.w,av.w,A1);
        A2=bdot(w2.x,av.x,A2); A2=bdot(w2.y,av.y,A2); A2=bdot(w2.z,av.z,A2); A2=bdot(w2.w,av.w,A2);
        A3=bdot(w3.x,av.x,A3); A3=bdot(w3.y,av.y,A3); A3=bdot(w3.z,av.z,A3); A3=bdot(w3.w,av.w,A3);
      }
      float ti = sigm(A3 - A2);
      float o0 = tanh_(A0)*(1.f - ti) + ti*tanh_(A1);
      float oh = __shfl_down(o0, 2);
      if (!(v & 1)){ u32 pk = packbf(o0, oh); hz[b][113+(v>>1)] = pk; xc2[b][v>>1] = pk; }
      if (t == TT-1) outh[b][216 + v] = o0;
    } else if (w == 8){
      if (t + 1 < TT && v < 261){
        int k0 = 2*(v-256), k1 = k0+1;
        float e0 = (k0 < 8) ? x[((size_t)bg*TT + t+1)*8 + k0] : dtp[(size_t)bg*TT + t+1];
        float e1 = (k1 < 8) ? x[((size_t)bg*TT + t+1)*8 + k1] : 0.f;
        hz[b][v-256] = packbf(e0, e1);
      }
    }
    __syncthreads();
    // ---- P7: CfC L2 -> i2 ----
    if (tid < 306){
      float A0=cb12, A1=cb22, A2=cba2, A3=cbb2;
      const u32* p = wl2 + v*(4*K2R);
      #pragma unroll 2
      for (int g = 0; g < K2R/4; ++g){
        uint4 av = *(const uint4*)&xc2[b][g<<2];
        const u32* q = p + (g<<2);
        uint4 w0 = *(const uint4*)q;
        uint4 w1 = *(const uint4*)(q + K2R);
        uint4 w2 = *(const uint4*)(q + 2*K2R);
        uint4 w3 = *(const uint4*)(q + 3*K2R);
        A0=bdot(w0.x,av.x,A0); A0=bdot(w0.y,av.y,A0); A0=bdot(w0.z,av.z,A0); A0=bdot(w0.w,av.w,A0);
        A1=bdot(w1.x,av.x,A1); A1=bdot(w1.y,av.y,A1); A1=bdot(w1.z,av.z,A1); A1=bdot(w1.w,av.w,A1);
        A2=bdot(w2.x,av.x,A2); A2=bdot(w2.y,av.y,A2); A2=bdot(w2.z,av.z,A2); A2=bdot(w2.w,av.w,A2);
        A3=bdot(w3.x,av.x,A3); A3=bdot(w3.y,av.y,A3); A3=bdot(w3.z,av.z,A3); A3=bdot(w3.w,av.w,A3);
      }
      float ti = sigm(A3 - A2);
      float o0 = tanh_(A0)*(1.f - ti) + ti*tanh_(A1);
      float oh = __shfl_down(o0, 2);
      if (!(v & 1)) hz[b][185+(v>>1)] = packbf(o0, oh);
      if (t == TT-1) outh[b][359 + v] = o0;
    }
    __syncthreads();
    // ---- per-step lockstep (perf-only; see soft_sync) ----
    if (t + 1 < TT) soft_sync(sync, (u32)(t + 1));
  }

  out[(size_t)bg*LATENT + v] = outh[b][v];
  out[65536 + (size_t)bg*LATENT + v] = creg;
}

extern "C" void kernel_launch(void* const* d_in, const int* in_sizes, int n_in,
                              void* d_out, int out_size, void* d_ws, size_t ws_size,
                              hipStream_t stream)
{
  (void)in_sizes; (void)n_in; (void)out_size; (void)ws_size;
  const float* x   = (const float*)d_in[0];
  const float* dt  = (const float*)d_in[1];
  const float* wi  = (const float*)d_in[2];
  const float* wr  = (const float*)d_in[3];
  const float* bi  = (const float*)d_in[4];
  const float* w10 = (const float*)d_in[5];  const float* b10 = (const float*)d_in[6];
  const float* w20 = (const float*)d_in[7];  const float* b20 = (const float*)d_in[8];
  const float* wa0 = (const float*)d_in[9];  const float* ba0 = (const float*)d_in[10];
  const float* wb0 = (const float*)d_in[11]; const float* bb0 = (const float*)d_in[12];
  const float* w11 = (const float*)d_in[13]; const float* b11 = (const float*)d_in[14];
  const float* w21 = (const float*)d_in[15]; const float* b21 = (const float*)d_in[16];
  const float* wa1 = (const float*)d_in[17]; const float* ba1 = (const float*)d_in[18];
  const float* wb1 = (const float*)d_in[19]; const float* bb1 = (const float*)d_in[20];
  const float* w12 = (const float*)d_in[21]; const float* b12 = (const float*)d_in[22];
  const float* w22 = (const float*)d_in[23]; const float* b22 = (const float*)d_in[24];
  const float* wa2 = (const float*)d_in[25]; const float* ba2 = (const float*)d_in[26];
  const float* wb2 = (const float*)d_in[27]; const float* bb2 = (const float*)d_in[28];
  const int* m0 = (const int*)d_in[29];
  const int* m1 = (const int*)d_in[30];
  const int* m2 = (const int*)d_in[31];

  u32* ws    = (u32*)d_ws;         // needs (WSY+WS_WORDS)*4 ≈ 3.34 MiB
  float* out = (float*)d_out;      // f32: h[128*512] then c[128*512]

  prep_kernel<<<dim3(856), dim3(1024), 0, stream>>>(
      wi, wr,
      w10,w20,wa0,wb0,m0,
      w11,w21,wa1,wb1,m1,
      w12,w22,wa2,wb2,m2,
      ws);

  liquid_rnn<<<dim3(NBLK), dim3(1024), 0, stream>>>(
      x, dt, bi,
      b10,b20,ba0,bb0,
      b11,b21,ba1,bb1,
      b12,b22,ba2,bb2,
      ws, out);
}

// Round 7
// 10229.913 us; speedup vs baseline: 1.7356x; 1.7356x over previous
//
#include <hip/hip_runtime.h>
#include <stdint.h>

typedef unsigned int u32;
typedef unsigned short u16;

#define TT 256

// ---- weight layout: all regions row-major [row][K-words] ----
#define LSW 272                         // LSTM row width in u32 words (544 slots)
#define OFF_L0  (2048*LSW)              // 557056
#define OFF_L1  (OFF_L0 + 864*128)      // 667648
#define OFF_L2  (OFF_L1 + 576*192)      // 778240
#define OFF_HL  (OFF_L2 + 640*160)      // 880640  h_lstm exchange: [128][264] u32 (u16[528])
#define OFF_REC (OFF_HL + 128*264)      // 914432  h_rec  exchange: [128][264] u32 (u16[528])
#define OFF_SYNC (OFF_REC + 128*264)    // 948224  barrier counters [4 phases][32 quads]
#define WS_TOTAL (OFF_SYNC + 256)       // 948480 u32 ≈ 3.62 MiB

__device__ __forceinline__ u16 f2bf(float f){
  u32 u = __builtin_bit_cast(u32, f);
  u += 0x7FFFu + ((u >> 16) & 1u);      // RNE
  return (u16)(u >> 16);
}
__device__ __forceinline__ u32 packbf(float lo, float hi){
  return (u32)f2bf(lo) | ((u32)f2bf(hi) << 16);
}
__device__ __forceinline__ float bdot(u32 a, u32 b, float c){
  float d;
  asm("v_dot2_f32_bf16 %0, %1, %2, %3" : "=v"(d) : "v"(a), "v"(b), "v"(c));
  return d;
}
__device__ __forceinline__ float sigm(float x){ return 1.0f/(1.0f + __expf(-x)); }
__device__ __forceinline__ float tanh_(float x){ return 1.0f - 2.0f/(1.0f + __expf(2.0f*x)); }

// cross-XCD exchange primitives: agent-scope relaxed atomics act at the
// coherence point (L3), so visibility never depends on XCD placement (G16).
__device__ __forceinline__ u32 xload(const u32* p){
  return __hip_atomic_load(p, __ATOMIC_RELAXED, __HIP_MEMORY_SCOPE_AGENT);
}
__device__ __forceinline__ void xstore16(u16* p, u16 v){
  __hip_atomic_store(p, v, __ATOMIC_RELAXED, __HIP_MEMORY_SCOPE_AGENT);
}

// 8-way per-quad barrier. __syncthreads drains each wave's stores (compiler
// emits s_waitcnt vmcnt(0) before s_barrier) so data is at L3 before arrive.
// Monotonic counters (prep zeroes each launch). Bounded spin: no hang possible.
__device__ __forceinline__ void quad_barrier(u32* cnt, u32 target){
  __syncthreads();
  if (threadIdx.x == 0){
    u32 n = __hip_atomic_fetch_add(cnt, 1u, __ATOMIC_RELAXED, __HIP_MEMORY_SCOPE_AGENT) + 1u;
    if (n < target){
      int guard = 1 << 18;
      while (__hip_atomic_load(cnt, __ATOMIC_RELAXED, __HIP_MEMORY_SCOPE_AGENT) < target
             && --guard) __builtin_amdgcn_s_sleep(4);
    }
  }
  __syncthreads();
  asm volatile("" ::: "memory");
}

// ---------------- weight value mappings (proven rounds 3-6) ----------------
__device__ __forceinline__ float lstmval(const float* wi, const float* wr, int r, int s){
  if (s < 9)  return wi[r*9 + s];
  if (s == 9 || s == 369 || s >= 523) return 0.f;
  if (s < 369) return wr[r*512 + s - 10];   // h0..h358
  return wr[r*512 + s - 11];                // h359..h511
}
__device__ __forceinline__ float l0val(const float* W, const int* M, int o, int k){
  if (k == 9 || k >= 226) return 0.f;
  int ki = (k < 9) ? k : k - 1;                 // D=225
  float w = W[o*225 + ki];
  if (M) w *= (float)M[o*225 + ki];
  return w;
}
__device__ __forceinline__ float l1val(const float* W, const int* M, int o, int k){
  if (k >= 359) return 0.f;                     // D=359
  float w = W[o*359 + k];
  if (M) w *= (float)M[o*359 + k];
  return w;
}
__device__ __forceinline__ float l2val(const float* W, const int* M, int o, int k){
  if (k == 143 || k == 144 || k >= 298) return 0.f;  // D=296; slot144 = h358 (zero weight)
  int ki = (k < 143) ? k : k - 2;
  float w = W[o*296 + ki];
  if (M) w *= (float)M[o*296 + ki];
  return w;
}

__global__ void prep_kernel(
    const float* __restrict__ wi, const float* __restrict__ wr,
    const float* __restrict__ w10,const float* __restrict__ w20,const float* __restrict__ wa0,const float* __restrict__ wb0,const int* __restrict__ m0,
    const float* __restrict__ w11,const float* __restrict__ w21,const float* __restrict__ wa1,const float* __restrict__ wb1,const int* __restrict__ m1,
    const float* __restrict__ w12,const float* __restrict__ w22,const float* __restrict__ wa2,const float* __restrict__ wb2,const int* __restrict__ m2,
    u32* __restrict__ ws)
{
  for (int i = blockIdx.x*blockDim.x + threadIdx.x; i < WS_TOTAL; i += gridDim.x*blockDim.x){
    float lo = 0.f, hi = 0.f;
    if (i < OFF_L0){
      int row = i / LSW, k2 = i - row*LSW;
      int orig = (row >> 2) + ((row & 3) << 9);   // gate-interleaved rows: r=4v+g
      lo = lstmval(wi, wr, orig, 2*k2);
      hi = lstmval(wi, wr, orig, 2*k2+1);
    } else if (i < OFF_L1){
      int loc = i - OFF_L0;
      int row = loc >> 7, k2 = loc & 127;
      int o = row >> 2, m = row & 3;
      const float* W = (m==0)?w10:(m==1)?w20:(m==2)?wa0:wb0;
      const int* M = (m < 2) ? m0 : nullptr;
      lo = l0val(W, M, o, 2*k2); hi = l0val(W, M, o, 2*k2+1);
    } else if (i < OFF_L2){
      int loc = i - OFF_L1;
      int row = loc / 192, k2 = loc - row*192;
      int o = row >> 2, m = row & 3;
      if (o < 143){
        const float* W = (m==0)?w11:(m==1)?w21:(m==2)?wa1:wb1;
        const int* M = (m < 2) ? m1 : nullptr;
        lo = l1val(W, M, o, 2*k2); hi = l1val(W, M, o, 2*k2+1);
      }
    } else if (i < OFF_HL){
      int loc = i - OFF_L2;
      int row = loc / 160, k2 = loc - row*160;
      int o = row >> 2, m = row & 3;
      if (o < 153){
        const float* W = (m==0)?w12:(m==1)?w22:(m==2)?wa2:wb2;
        const int* M = (m < 2) ? m2 : nullptr;
        lo = l2val(W, M, o, 2*k2); hi = l2val(W, M, o, 2*k2+1);
      }
    } else {
      ws[i] = 0u;                 // exchange arrays (h_rec(0)=0) + sync counters
      continue;
    }
    ws[i] = packbf(lo, hi);
  }
}

// ---------------- weight-stationary sliced persistent kernel ----------------
// grid 256 = 8 slices x 32 quads; block: slice s = bid&7 (-> XCD s under the
// round-robin mapping; perf-only assumption), quad = bid>>3 owns batches 4q..4q+3.
// thread: b4 = tid&3 (batch), rr = tid>>2 (row within slice). Lanes 0-3 share a
// weight row -> 4-way coalescer dedup. Per-XCD L2 weight footprint ~440 KB.
__global__ __launch_bounds__(1024) void liquid_rnn(
    const float* __restrict__ x, const float* __restrict__ dtp,
    const float* __restrict__ lstm_bi,
    const float* __restrict__ b10, const float* __restrict__ b20,
    const float* __restrict__ ba0, const float* __restrict__ bb0,
    const float* __restrict__ b11, const float* __restrict__ b21,
    const float* __restrict__ ba1, const float* __restrict__ bb1,
    const float* __restrict__ b12, const float* __restrict__ b22,
    const float* __restrict__ ba2, const float* __restrict__ bb2,
    u32* __restrict__ ws, float* __restrict__ out)
{
  __shared__ u32 xcS[4][272];     // shared activation staging (per local batch)

  const int tid  = threadIdx.x;
  const int bid  = blockIdx.x;
  const int s    = bid & 7;
  const int quad = bid >> 3;
  const int b4   = tid & 3;
  const int rr   = tid >> 2;            // 0..255
  const int batch= quad*4 + b4;         // my global batch (for compute threads)

  u32* hlw  = ws + OFF_HL;
  u32* recw = ws + OFF_REC;
  u16* hl16 = (u16*)hlw;
  u16* rec16= (u16*)recw;
  u32* sync = ws + OFF_SYNC;

  // ---- hoisted per-thread constants ----
  const int vA = s*64 + (rr >> 2);          // LSTM neuron of my row group
  const float lb = lstm_bi[vA + 512*(rr & 3)];
  int oB = 0; float biasB = 0.f;
  if (tid < 432){ int m = rr & 3; oB = 27*s + (rr >> 2);
    biasB = ((m==0)?b10:(m==1)?b20:(m==2)?ba0:bb0)[oB]; }
  int oC = 0; float biasC = 0.f;
  if (tid < 288){ int m = rr & 3; oC = 18*s + (rr >> 2);
    if (oC < 143) biasC = ((m==0)?b11:(m==1)?b21:(m==2)?ba1:bb1)[oC]; }
  int oD = 0; float biasD = 0.f;
  if (tid < 320){ int m = rr & 3; oD = 20*s + (rr >> 2);
    if (oD < 153) biasD = ((m==0)?b12:(m==1)?b22:(m==2)?ba2:bb2)[oD]; }

  // zero xcS (stale slots must be finite; pad words stay 0 forever)
  for (int i = tid; i < 4*272; i += 1024) ((u32*)xcS)[i] = 0u;
  float creg = 0.f;
  __syncthreads();

  for (int t = 0; t < TT; ++t){
    const u32 tgt = 8u*(u32)(t+1);
    // ================= phase A: LSTM (rows 256s..256s+255) =================
    if (tid < 20){                              // xt words 0..4 per local batch
      int bb = tid/5, w = tid - bb*5;
      int bg = quad*4 + bb;
      float e0, e1;
      if (w < 4){ e0 = x[((size_t)bg*TT + t)*8 + 2*w]; e1 = x[((size_t)bg*TT + t)*8 + 2*w+1]; }
      else      { e0 = dtp[(size_t)bg*TT + t]; e1 = 0.f; }
      xcS[bb][w] = packbf(e0, e1);
    }
    { int bb = tid >> 8, w = tid & 255;         // rec words 0..255
      xcS[bb][5+w] = xload(&recw[(size_t)(quad*4+bb)*264 + w]); }
    if (tid < 4) xcS[tid][261] = xload(&recw[(size_t)(quad*4+tid)*264 + 256]);
    __syncthreads();
    {
      float A = lb;
      const u32* wrow = ws + (size_t)(s*256 + rr)*LSW;
      #pragma unroll 4
      for (int g = 0; g < 68; ++g){
        uint4 wv = *(const uint4*)(wrow + (g<<2));
        uint4 av = *(const uint4*)&xcS[b4][g<<2];
        A = bdot(wv.x, av.x, A); A = bdot(wv.y, av.y, A);
        A = bdot(wv.z, av.z, A); A = bdot(wv.w, av.w, A);
      }
      float zig = __shfl_down(A, 4), zfg = __shfl_down(A, 8), zog = __shfl_down(A, 12);
      if (!(rr & 3)){
        creg = creg * sigm(zfg + 1.0f) + tanh_(A) * sigm(zig);
        float hl = tanh_(creg) * sigm(zog);
        xstore16(&hl16[(size_t)batch*528 + vA], f2bf(hl));
      }
    }
    quad_barrier(&sync[quad], tgt);
    // ================= phase B: CfC L0 (outputs 27s..27s+26) =================
    if (tid < 432){ int bb = tid/108, j = tid - bb*108;       // hl pairs 0..107
      xcS[bb][5+j] = xload(&hlw[(size_t)(quad*4+bb)*264 + j]); }
    __syncthreads();
    if (tid < 432){
      float A = biasB;
      const u32* wrow = ws + OFF_L0 + (size_t)(s*108 + rr)*128;
      #pragma unroll 2
      for (int g = 0; g < 30; ++g){
        uint4 wv = *(const uint4*)(wrow + (g<<2));
        uint4 av = *(const uint4*)&xcS[b4][g<<2];
        A = bdot(wv.x, av.x, A); A = bdot(wv.y, av.y, A);
        A = bdot(wv.z, av.z, A); A = bdot(wv.w, av.w, A);
      }
      float A1 = __shfl_down(A, 4), A2 = __shfl_down(A, 8), A3 = __shfl_down(A, 12);
      if (!(rr & 3)){
        float ti = sigm(A3 - A2);
        float o0 = tanh_(A)*(1.f - ti) + ti*tanh_(A1);
        xstore16(&rec16[(size_t)batch*528 + oB], f2bf(o0));
        if (t == TT-1) out[(size_t)batch*512 + oB] = o0;
      }
    }
    quad_barrier(&sync[32+quad], tgt);
    // ================= phase C: CfC L1 (outputs 18s.., guard <143) =================
    if (tid < 720){ int bb = tid/180, j = tid - bb*180;
      u32 v = (j < 108) ? xload(&recw[(size_t)(quad*4+bb)*264 + j])    // i0 pairs
                        : xload(&hlw[(size_t)(quad*4+bb)*264 + j]);    // hl pairs 108..179
      xcS[bb][j] = v; }
    __syncthreads();
    if (tid < 288){
      float A = biasC;
      const u32* wrow = ws + OFF_L1 + (size_t)(s*72 + rr)*192;
      #pragma unroll 4
      for (int g = 0; g < 48; ++g){
        uint4 wv = *(const uint4*)(wrow + (g<<2));
        uint4 av = *(const uint4*)&xcS[b4][g<<2];
        A = bdot(wv.x, av.x, A); A = bdot(wv.y, av.y, A);
        A = bdot(wv.z, av.z, A); A = bdot(wv.w, av.w, A);
      }
      float A1 = __shfl_down(A, 4), A2 = __shfl_down(A, 8), A3 = __shfl_down(A, 12);
      if (!(rr & 3) && oC < 143){
        float ti = sigm(A3 - A2);
        float o0 = tanh_(A)*(1.f - ti) + ti*tanh_(A1);
        xstore16(&rec16[(size_t)batch*528 + 216 + oC], f2bf(o0));
        if (t == TT-1) out[(size_t)batch*512 + 216 + oC] = o0;
      }
    }
    quad_barrier(&sync[64+quad], tgt);
    // ================= phase D: CfC L2 (outputs 20s.., guard <153) =================
    if (tid < 596){ int bb = tid/149, j = tid - bb*149;
      u32 v;
      if (j < 72)      v = xload(&recw[(size_t)(quad*4+bb)*264 + 108 + j]);  // i1 pairs
      else if (j == 72) v = xload(&hlw[(size_t)(quad*4+bb)*264 + 179]);      // (h358,h359)
      else              v = xload(&hlw[(size_t)(quad*4+bb)*264 + 180 + (j-73)]);
      xcS[bb][j] = v; }
    __syncthreads();
    if (tid < 320){
      float A = biasD;
      const u32* wrow = ws + OFF_L2 + (size_t)(s*80 + rr)*160;
      #pragma unroll 4
      for (int g = 0; g < 40; ++g){
        uint4 wv = *(const uint4*)(wrow + (g<<2));
        uint4 av = *(const uint4*)&xcS[b4][g<<2];
        A = bdot(wv.x, av.x, A); A = bdot(wv.y, av.y, A);
        A = bdot(wv.z, av.z, A); A = bdot(wv.w, av.w, A);
      }
      float A1 = __shfl_down(A, 4), A2 = __shfl_down(A, 8), A3 = __shfl_down(A, 12);
      if (!(rr & 3) && oD < 153){
        float ti = sigm(A3 - A2);
        float o0 = tanh_(A)*(1.f - ti) + ti*tanh_(A1);
        xstore16(&rec16[(size_t)batch*528 + 360 + oD], f2bf(o0));
        if (t == TT-1) out[(size_t)batch*512 + 359 + oD] = o0;
      }
    }
    quad_barrier(&sync[96+quad], tgt);
  }

  if (!(rr & 3)) out[65536 + (size_t)batch*512 + vA] = creg;
}

extern "C" void kernel_launch(void* const* d_in, const int* in_sizes, int n_in,
                              void* d_out, int out_size, void* d_ws, size_t ws_size,
                              hipStream_t stream)
{
  (void)in_sizes; (void)n_in; (void)out_size; (void)ws_size;
  const float* x   = (const float*)d_in[0];
  const float* dt  = (const float*)d_in[1];
  const float* wi  = (const float*)d_in[2];
  const float* wr  = (const float*)d_in[3];
  const float* bi  = (const float*)d_in[4];
  const float* w10 = (const float*)d_in[5];  const float* b10 = (const float*)d_in[6];
  const float* w20 = (const float*)d_in[7];  const float* b20 = (const float*)d_in[8];
  const float* wa0 = (const float*)d_in[9];  const float* ba0 = (const float*)d_in[10];
  const float* wb0 = (const float*)d_in[11]; const float* bb0 = (const float*)d_in[12];
  const float* w11 = (const float*)d_in[13]; const float* b11 = (const float*)d_in[14];
  const float* w21 = (const float*)d_in[15]; const float* b21 = (const float*)d_in[16];
  const float* wa1 = (const float*)d_in[17]; const float* ba1 = (const float*)d_in[18];
  const float* wb1 = (const float*)d_in[19]; const float* bb1 = (const float*)d_in[20];
  const float* w12 = (const float*)d_in[21]; const float* b12 = (const float*)d_in[22];
  const float* w22 = (const float*)d_in[23]; const float* b22 = (const float*)d_in[24];
  const float* wa2 = (const float*)d_in[25]; const float* ba2 = (const float*)d_in[26];
  const float* wb2 = (const float*)d_in[27]; const float* bb2 = (const float*)d_in[28];
  const int* m0 = (const int*)d_in[29];
  const int* m1 = (const int*)d_in[30];
  const int* m2 = (const int*)d_in[31];

  u32* ws    = (u32*)d_ws;         // needs WS_TOTAL*4 ≈ 3.62 MiB
  float* out = (float*)d_out;      // f32: h[128*512] then c[128*512]

  prep_kernel<<<dim3(927), dim3(1024), 0, stream>>>(
      wi, wr,
      w10,w20,wa0,wb0,m0,
      w11,w21,wa1,wb1,m1,
      w12,w22,wa2,wb2,m2,
      ws);

  liquid_rnn<<<dim3(256), dim3(1024), 0, stream>>>(
      x, dt, bi,
      b10,b20,ba0,bb0,
      b11,b21,ba1,bb1,
      b12,b22,ba2,bb2,
      ws, out);
}

// Round 8
// 6057.994 us; speedup vs baseline: 2.9309x; 1.6887x over previous
//
#include <hip/hip_runtime.h>
#include <stdint.h>

typedef unsigned int u32;
typedef unsigned short u16;

#define TT 256

// ---- weight layout: all regions row-major [row][K-words] ----
#define LSW 272                         // LSTM row width in u32 words (544 slots)
#define OFF_L0  (2048*LSW)              // 557056
#define OFF_L1  (OFF_L0 + 864*128)      // 667648
#define OFF_L2  (OFF_L1 + 576*192)      // 778240
#define OFF_HL  (OFF_L2 + 640*160)      // 880640  h_lstm exchange: [128][264] u32 (u16[528])
#define OFF_REC (OFF_HL + 128*264)      // 914432  h_rec  exchange: [128][264] u32 (u16[528])
#define OFF_SYNC (OFF_REC + 128*264)    // 948224  flags: [32 quads][8 slices][16 words]
#define WS_TOTAL (OFF_SYNC + 4096)      // 952320 u32 ≈ 3.63 MiB
#define NFL 16                          // flag padding: 64 B per block -> no RMW contention

__device__ __forceinline__ u16 f2bf(float f){
  u32 u = __builtin_bit_cast(u32, f);
  u += 0x7FFFu + ((u >> 16) & 1u);      // RNE
  return (u16)(u >> 16);
}
__device__ __forceinline__ u32 packbf(float lo, float hi){
  return (u32)f2bf(lo) | ((u32)f2bf(hi) << 16);
}
__device__ __forceinline__ float bdot(u32 a, u32 b, float c){
  float d;
  asm("v_dot2_f32_bf16 %0, %1, %2, %3" : "=v"(d) : "v"(a), "v"(b), "v"(c));
  return d;
}
__device__ __forceinline__ float sigm(float x){ return 1.0f/(1.0f + __expf(-x)); }
__device__ __forceinline__ float tanh_(float x){ return 1.0f - 2.0f/(1.0f + __expf(2.0f*x)); }

// cross-XCD exchange: agent-scope relaxed atomics act at the coherence point
// (L3), so visibility never depends on XCD placement (G16).
__device__ __forceinline__ u32 xload(const u32* p){
  return __hip_atomic_load(p, __ATOMIC_RELAXED, __HIP_MEMORY_SCOPE_AGENT);
}
__device__ __forceinline__ void xstore16(u16* p, u16 v){
  __hip_atomic_store(p, v, __ATOMIC_RELAXED, __HIP_MEMORY_SCOPE_AGENT);
}

// Flag barrier (monotonic, per-block flag line -> no RMW serialization).
// arrive: __syncthreads drains every wave's sc1 stores (compiler emits
// s_waitcnt vmcnt(0) before s_barrier) => data globally visible, then one
// relaxed flag store. wait: lanes 0..7 poll the 8 quad flags in parallel
// (one gather/iter); bounded spin -> hang impossible (same mechanism that
// ran correct in round 7, minus the serialized counter).
__device__ __forceinline__ void bar_arrive(u32* fl, int s, u32 v){
  __syncthreads();
  if (threadIdx.x == 0)
    __hip_atomic_store(&fl[s*NFL], v, __ATOMIC_RELAXED, __HIP_MEMORY_SCOPE_AGENT);
}
__device__ __forceinline__ void bar_wait(const u32* fl, u32 v){
  if (threadIdx.x < 8){
    int guard = 1 << 16;
    while (__hip_atomic_load(&fl[threadIdx.x*NFL], __ATOMIC_RELAXED, __HIP_MEMORY_SCOPE_AGENT) < v
           && --guard) __builtin_amdgcn_s_sleep(1);
  }
  __syncthreads();
  asm volatile("" ::: "memory");
}

// ---------------- weight value mappings (proven rounds 3-7) ----------------
__device__ __forceinline__ float lstmval(const float* wi, const float* wr, int r, int s){
  if (s < 9)  return wi[r*9 + s];
  if (s == 9 || s == 369 || s >= 523) return 0.f;
  if (s < 369) return wr[r*512 + s - 10];   // h0..h358
  return wr[r*512 + s - 11];                // h359..h511
}
__device__ __forceinline__ float l0val(const float* W, const int* M, int o, int k){
  if (k == 9 || k >= 226) return 0.f;
  int ki = (k < 9) ? k : k - 1;                 // D=225
  float w = W[o*225 + ki];
  if (M) w *= (float)M[o*225 + ki];
  return w;
}
__device__ __forceinline__ float l1val(const float* W, const int* M, int o, int k){
  if (k >= 359) return 0.f;                     // D=359
  float w = W[o*359 + k];
  if (M) w *= (float)M[o*359 + k];
  return w;
}
__device__ __forceinline__ float l2val(const float* W, const int* M, int o, int k){
  if (k == 143 || k == 144 || k >= 298) return 0.f;  // D=296; slot144 = h358 (zero weight)
  int ki = (k < 143) ? k : k - 2;
  float w = W[o*296 + ki];
  if (M) w *= (float)M[o*296 + ki];
  return w;
}

__global__ void prep_kernel(
    const float* __restrict__ wi, const float* __restrict__ wr,
    const float* __restrict__ w10,const float* __restrict__ w20,const float* __restrict__ wa0,const float* __restrict__ wb0,const int* __restrict__ m0,
    const float* __restrict__ w11,const float* __restrict__ w21,const float* __restrict__ wa1,const float* __restrict__ wb1,const int* __restrict__ m1,
    const float* __restrict__ w12,const float* __restrict__ w22,const float* __restrict__ wa2,const float* __restrict__ wb2,const int* __restrict__ m2,
    u32* __restrict__ ws)
{
  for (int i = blockIdx.x*blockDim.x + threadIdx.x; i < WS_TOTAL; i += gridDim.x*blockDim.x){
    float lo = 0.f, hi = 0.f;
    if (i < OFF_L0){
      int row = i / LSW, k2 = i - row*LSW;
      int orig = (row >> 2) + ((row & 3) << 9);   // gate-interleaved rows: r=4v+g
      lo = lstmval(wi, wr, orig, 2*k2);
      hi = lstmval(wi, wr, orig, 2*k2+1);
    } else if (i < OFF_L1){
      int loc = i - OFF_L0;
      int row = loc >> 7, k2 = loc & 127;
      int o = row >> 2, m = row & 3;
      const float* W = (m==0)?w10:(m==1)?w20:(m==2)?wa0:wb0;
      const int* M = (m < 2) ? m0 : nullptr;
      lo = l0val(W, M, o, 2*k2); hi = l0val(W, M, o, 2*k2+1);
    } else if (i < OFF_L2){
      int loc = i - OFF_L1;
      int row = loc / 192, k2 = loc - row*192;
      int o = row >> 2, m = row & 3;
      if (o < 143){
        const float* W = (m==0)?w11:(m==1)?w21:(m==2)?wa1:wb1;
        const int* M = (m < 2) ? m1 : nullptr;
        lo = l1val(W, M, o, 2*k2); hi = l1val(W, M, o, 2*k2+1);
      }
    } else if (i < OFF_HL){
      int loc = i - OFF_L2;
      int row = loc / 160, k2 = loc - row*160;
      int o = row >> 2, m = row & 3;
      if (o < 153){
        const float* W = (m==0)?w12:(m==1)?w22:(m==2)?wa2:wb2;
        const int* M = (m < 2) ? m2 : nullptr;
        lo = l2val(W, M, o, 2*k2); hi = l2val(W, M, o, 2*k2+1);
      }
    } else {
      ws[i] = 0u;                 // exchange arrays (h_rec(0)=0) + flags
      continue;
    }
    ws[i] = packbf(lo, hi);
  }
}

// ---------------- weight-stationary sliced persistent kernel ----------------
// grid 256 = 8 slices x 32 quads; slice s = bid&7 (-> XCD s under round-robin;
// perf-only), quad = bid>>3 owns batches 4q..4q+3. thread: b4 = tid&3 (batch),
// rr = tid>>2 (row in slice). Lanes 0-3 share a weight row -> 4-way dedup.
__global__ __launch_bounds__(1024) void liquid_rnn(
    const float* __restrict__ x, const float* __restrict__ dtp,
    const float* __restrict__ lstm_bi,
    const float* __restrict__ b10, const float* __restrict__ b20,
    const float* __restrict__ ba0, const float* __restrict__ bb0,
    const float* __restrict__ b11, const float* __restrict__ b21,
    const float* __restrict__ ba1, const float* __restrict__ bb1,
    const float* __restrict__ b12, const float* __restrict__ b22,
    const float* __restrict__ ba2, const float* __restrict__ bb2,
    u32* __restrict__ ws, float* __restrict__ out)
{
  __shared__ u32 xcS[4][272];     // activation staging (per local batch)

  const int tid  = threadIdx.x;
  const int bid  = blockIdx.x;
  const int s    = bid & 7;
  const int quad = bid >> 3;
  const int b4   = tid & 3;
  const int rr   = tid >> 2;            // 0..255
  const int batch= quad*4 + b4;

  u32* hlw  = ws + OFF_HL;
  u32* recw = ws + OFF_REC;
  u16* hl16 = (u16*)hlw;
  u16* rec16= (u16*)recw;
  u32* fl   = ws + OFF_SYNC + quad*(8*NFL);

  // ---- hoisted per-thread constants ----
  const int vA = s*64 + (rr >> 2);          // LSTM neuron of my row group
  const float lb = lstm_bi[vA + 512*(rr & 3)];
  int oB = 0; float biasB = 0.f;
  if (tid < 432){ int m = rr & 3; oB = 27*s + (rr >> 2);
    biasB = ((m==0)?b10:(m==1)?b20:(m==2)?ba0:bb0)[oB]; }
  int oC = 0; float biasC = 0.f;
  if (tid < 288){ int m = rr & 3; oC = 18*s + (rr >> 2);
    if (oC < 143) biasC = ((m==0)?b11:(m==1)?b21:(m==2)?ba1:bb1)[oC]; }
  int oD = 0; float biasD = 0.f;
  if (tid < 320){ int m = rr & 3; oD = 20*s + (rr >> 2);
    if (oD < 153) biasD = ((m==0)?b12:(m==1)?b22:(m==2)?ba2:bb2)[oD]; }

  for (int i = tid; i < 4*272; i += 1024) ((u32*)xcS)[i] = 0u;
  float creg = 0.f;
  __syncthreads();

  for (int t = 0; t < TT; ++t){
    const u32 vb = 4u*(u32)t;
    // ========== A staging: overlap with pending D(t-1) wait ==========
    if (tid < 20){                              // xt words 0..4 (LDS-local: safe,
      int bb = tid/5, w = tid - bb*5;           // D compute synced before arrive)
      int bg = quad*4 + bb;
      float e0, e1;
      if (w < 4){ e0 = x[((size_t)bg*TT + t)*8 + 2*w]; e1 = x[((size_t)bg*TT + t)*8 + 2*w+1]; }
      else      { e0 = dtp[(size_t)bg*TT + t]; e1 = 0.f; }
      xcS[bb][w] = packbf(e0, e1);
    }
    if (tid < 720){                             // i0,i1 pairs: final since bars 2,3
      int bb = tid/180, j = tid - bb*180;       // of step t-1; next writes gated on
      xcS[bb][5+j] = xload(&recw[(size_t)(quad*4+bb)*264 + j]);  // my own arrives
    }
    bar_wait(fl, vb);                           // all slices' D(t-1) done (t=0: no-op)
    { int bb = tid >> 8, w = tid & 255;         // i2 pairs (words 180..255)
      if (w >= 180) xcS[bb][5+w] = xload(&recw[(size_t)(quad*4+bb)*264 + w]); }
    if (tid < 4) xcS[tid][261] = xload(&recw[(size_t)(quad*4+tid)*264 + 256]);
    __syncthreads();
    // ================= phase A: LSTM (rows 256s..256s+255) =================
    {
      float A = lb;
      const u32* wrow = ws + (size_t)(s*256 + rr)*LSW;
      #pragma unroll 4
      for (int g = 0; g < 68; ++g){
        uint4 wv = *(const uint4*)(wrow + (g<<2));
        uint4 av = *(const uint4*)&xcS[b4][g<<2];
        A = bdot(wv.x, av.x, A); A = bdot(wv.y, av.y, A);
        A = bdot(wv.z, av.z, A); A = bdot(wv.w, av.w, A);
      }
      float zig = __shfl_down(A, 4), zfg = __shfl_down(A, 8), zog = __shfl_down(A, 12);
      if (!(rr & 3)){
        creg = creg * sigm(zfg + 1.0f) + tanh_(A) * sigm(zig);
        float hl = tanh_(creg) * sigm(zog);
        xstore16(&hl16[(size_t)batch*528 + vA], f2bf(hl));
      }
    }
    bar_arrive(fl, s, vb+1);  bar_wait(fl, vb+1);
    // ================= phase B: CfC L0 (outputs 27s..27s+26) =================
    if (tid < 432){ int bb = tid/108, j = tid - bb*108;       // hl pairs 0..107
      xcS[bb][5+j] = xload(&hlw[(size_t)(quad*4+bb)*264 + j]); }
    __syncthreads();
    if (tid < 432){
      float A = biasB;
      const u32* wrow = ws + OFF_L0 + (size_t)(s*108 + rr)*128;
      #pragma unroll 2
      for (int g = 0; g < 30; ++g){
        uint4 wv = *(const uint4*)(wrow + (g<<2));
        uint4 av = *(const uint4*)&xcS[b4][g<<2];
        A = bdot(wv.x, av.x, A); A = bdot(wv.y, av.y, A);
        A = bdot(wv.z, av.z, A); A = bdot(wv.w, av.w, A);
      }
      float A1 = __shfl_down(A, 4), A2 = __shfl_down(A, 8), A3 = __shfl_down(A, 12);
      if (!(rr & 3)){
        float ti = sigm(A3 - A2);
        float o0 = tanh_(A)*(1.f - ti) + ti*tanh_(A1);
        xstore16(&rec16[(size_t)batch*528 + oB], f2bf(o0));
        if (t == TT-1) out[(size_t)batch*512 + oB] = o0;
      }
    }
    bar_arrive(fl, s, vb+2);  bar_wait(fl, vb+2);
    // ================= phase C: CfC L1 (outputs 18s.., guard <143) =================
    if (tid < 720){ int bb = tid/180, j = tid - bb*180;
      u32 v = (j < 108) ? xload(&recw[(size_t)(quad*4+bb)*264 + j])    // i0 pairs
                        : xload(&hlw[(size_t)(quad*4+bb)*264 + j]);    // hl 108..179
      xcS[bb][j] = v; }
    __syncthreads();
    if (tid < 288){
      float A = biasC;
      const u32* wrow = ws + OFF_L1 + (size_t)(s*72 + rr)*192;
      #pragma unroll 4
      for (int g = 0; g < 48; ++g){
        uint4 wv = *(const uint4*)(wrow + (g<<2));
        uint4 av = *(const uint4*)&xcS[b4][g<<2];
        A = bdot(wv.x, av.x, A); A = bdot(wv.y, av.y, A);
        A = bdot(wv.z, av.z, A); A = bdot(wv.w, av.w, A);
      }
      float A1 = __shfl_down(A, 4), A2 = __shfl_down(A, 8), A3 = __shfl_down(A, 12);
      if (!(rr & 3) && oC < 143){
        float ti = sigm(A3 - A2);
        float o0 = tanh_(A)*(1.f - ti) + ti*tanh_(A1);
        xstore16(&rec16[(size_t)batch*528 + 216 + oC], f2bf(o0));
        if (t == TT-1) out[(size_t)batch*512 + 216 + oC] = o0;
      }
    }
    bar_arrive(fl, s, vb+3);  bar_wait(fl, vb+3);
    // ================= phase D: CfC L2 (outputs 20s.., guard <153) =================
    if (tid < 596){ int bb = tid/149, j = tid - bb*149;
      u32 v;
      if (j < 72)      v = xload(&recw[(size_t)(quad*4+bb)*264 + 108 + j]);  // i1
      else if (j == 72) v = xload(&hlw[(size_t)(quad*4+bb)*264 + 179]);      // (h358,h359)
      else              v = xload(&hlw[(size_t)(quad*4+bb)*264 + 180 + (j-73)]);
      xcS[bb][j] = v; }
    __syncthreads();
    if (tid < 320){
      float A = biasD;
      const u32* wrow = ws + OFF_L2 + (size_t)(s*80 + rr)*160;
      #pragma unroll 4
      for (int g = 0; g < 40; ++g){
        uint4 wv = *(const uint4*)(wrow + (g<<2));
        uint4 av = *(const uint4*)&xcS[b4][g<<2];
        A = bdot(wv.x, av.x, A); A = bdot(wv.y, av.y, A);
        A = bdot(wv.z, av.z, A); A = bdot(wv.w, av.w, A);
      }
      float A1 = __shfl_down(A, 4), A2 = __shfl_down(A, 8), A3 = __shfl_down(A, 12);
      if (!(rr & 3) && oD < 153){
        float ti = sigm(A3 - A2);
        float o0 = tanh_(A)*(1.f - ti) + ti*tanh_(A1);
        xstore16(&rec16[(size_t)batch*528 + 360 + oD], f2bf(o0));
        if (t == TT-1) out[(size_t)batch*512 + 359 + oD] = o0;
      }
    }
    bar_arrive(fl, s, vb+4);   // wait deferred to next iteration's loop top
  }

  if (!(rr & 3)) out[65536 + (size_t)batch*512 + vA] = creg;
}

extern "C" void kernel_launch(void* const* d_in, const int* in_sizes, int n_in,
                              void* d_out, int out_size, void* d_ws, size_t ws_size,
                              hipStream_t stream)
{
  (void)in_sizes; (void)n_in; (void)out_size; (void)ws_size;
  const float* x   = (const float*)d_in[0];
  const float* dt  = (const float*)d_in[1];
  const float* wi  = (const float*)d_in[2];
  const float* wr  = (const float*)d_in[3];
  const float* bi  = (const float*)d_in[4];
  const float* w10 = (const float*)d_in[5];  const float* b10 = (const float*)d_in[6];
  const float* w20 = (const float*)d_in[7];  const float* b20 = (const float*)d_in[8];
  const float* wa0 = (const float*)d_in[9];  const float* ba0 = (const float*)d_in[10];
  const float* wb0 = (const float*)d_in[11]; const float* bb0 = (const float*)d_in[12];
  const float* w11 = (const float*)d_in[13]; const float* b11 = (const float*)d_in[14];
  const float* w21 = (const float*)d_in[15]; const float* b21 = (const float*)d_in[16];
  const float* wa1 = (const float*)d_in[17]; const float* ba1 = (const float*)d_in[18];
  const float* wb1 = (const float*)d_in[19]; const float* bb1 = (const float*)d_in[20];
  const float* w12 = (const float*)d_in[21]; const float* b12 = (const float*)d_in[22];
  const float* w22 = (const float*)d_in[23]; const float* b22 = (const float*)d_in[24];
  const float* wa2 = (const float*)d_in[25]; const float* ba2 = (const float*)d_in[26];
  const float* wb2 = (const float*)d_in[27]; const float* bb2 = (const float*)d_in[28];
  const int* m0 = (const int*)d_in[29];
  const int* m1 = (const int*)d_in[30];
  const int* m2 = (const int*)d_in[31];

  u32* ws    = (u32*)d_ws;         // needs WS_TOTAL*4 ≈ 3.63 MiB
  float* out = (float*)d_out;      // f32: h[128*512] then c[128*512]

  prep_kernel<<<dim3(931), dim3(1024), 0, stream>>>(
      wi, wr,
      w10,w20,wa0,wb0,m0,
      w11,w21,wa1,wb1,m1,
      w12,w22,wa2,wb2,m2,
      ws);

  liquid_rnn<<<dim3(256), dim3(1024), 0, stream>>>(
      x, dt, bi,
      b10,b20,ba0,bb0,
      b11,b21,ba1,bb1,
      b12,b22,ba2,bb2,
      ws, out);
}